// Round 7
// baseline (154.835 us; speedup 1.0000x reference)
//
#include <hip/hip_runtime.h>
#include <hip/hip_bf16.h>

// Problem constants (B,T,C,H from reference)
#define BATCH 8
#define SEQ   2048
#define EMB   1024
#define HD    128

typedef __attribute__((ext_vector_type(8))) short bf16x8;  // MFMA A/B frag (4 VGPR)
typedef __attribute__((ext_vector_type(4))) float f32x4;   // MFMA C/D frag

__device__ __forceinline__ short f2bf(float f) {           // RNE
    union { float f; unsigned u; } v; v.f = f;
    unsigned r = v.u + 0x7fffu + ((v.u >> 16) & 1u);
    return (short)(r >> 16);
}

// async global->LDS 16B/lane copy (wave-uniform LDS base + lane*16, per-lane src)
__device__ __forceinline__ void glds16(const short* g, short* l) {
    __builtin_amdgcn_global_load_lds(
        (const __attribute__((address_space(1))) unsigned int*)g,
        (__attribute__((address_space(3))) unsigned int*)l, 16, 0, 0);
}

// ===========================================================================
// FRAGMENT-IMAGE LAYOUTS (R6-verified): every MFMA fragment = one contiguous
// 1KB region = one fully-coalesced 16B/lane load for the consuming wave.
// W image (nh 0=K,1=V; k-chunk kc): slot(kk,f,l,q) -> W[nh*128+f*16+l][kc*64+kk*32+q*8+e]
// K image (b, jt): slot(kc,js,l,q) -> K[js*16+l][kc*32+q*8+e]
// V image (b, jt): slot(jc,f,l,q)  -> V[jc*32+q*8+e][f*16+l]
// ===========================================================================

__global__ void prep_w(const float* __restrict__ Wk, const float* __restrict__ Wv,
                       short* __restrict__ Wimg) {
    int g  = blockIdx.x * 256 + threadIdx.x;   // 0..32767
    int q  = g & 3;
    int l  = (g >> 2) & 15;
    int f  = (g >> 6) & 7;
    int kk = (g >> 9) & 1;
    int kc = (g >> 10) & 15;
    int nh = (g >> 14) & 1;
    const float* src = (nh ? Wv : Wk) + (size_t)(f * 16 + l) * EMB + kc * 64 + kk * 32 + q * 8;
    float4 f0 = *(const float4*)src;
    float4 f1 = *(const float4*)(src + 4);
    bf16x8 v;
    v[0]=f2bf(f0.x); v[1]=f2bf(f0.y); v[2]=f2bf(f0.z); v[3]=f2bf(f0.w);
    v[4]=f2bf(f1.x); v[5]=f2bf(f1.y); v[6]=f2bf(f1.z); v[7]=f2bf(f1.w);
    *(bf16x8*)&Wimg[(size_t)g * 8] = v;
}

// ---------------------------------------------------------------------------
// proj_kernel v8 VERBATIM (R8/R9-verified ~30us; R11's M=32 restructure
// REGRESSED +5us -- do not retry): [K|V] = x @ [Wk|Wv]^T. One block per
// 64-row tile computes BOTH K and V (x read once); W B-frags load directly
// from the global W-image (contiguous 1KB/wave, L2-resident). LDS = A dbuf
// only. Grid 256 x 512thr.
// ---------------------------------------------------------------------------
__global__ __launch_bounds__(512, 2)
void proj_kernel(const float* __restrict__ x, const short* __restrict__ Wimg,
                 short* __restrict__ Kimg,    // [8][32] 16KB images
                 short* __restrict__ Vimg)    // [8][32] 16KB images
{
    __shared__ __align__(16) union {
        short A[2][64][72];          // 18.4 KB A staging dbuf (+8 pad rows)
        short ep[16384];             // 32 KB epilogue: [K image | V image]
    } sm;

    const int tid  = threadIdx.x;
    const int wave = tid >> 6;
    const int lane = tid & 63;
    const int quad = lane >> 4;
    const int l16  = lane & 15;
    const int nh   = wave >> 2;        // 0 = K half, 1 = V half
    const int fb   = (wave & 3) * 2;   // f-pair base within the half
    const int mt   = blockIdx.x;       // 0..255 (64-row tile)
    const int row0 = mt * 64;

    const int srow = tid >> 3, sseg = tid & 7;
    const float* xsrc = x + (size_t)(row0 + srow) * EMB + sseg * 8;
    const short* wsrc = Wimg + (size_t)nh * 131072;

    f32x4 acc[4][2];                   // [mf][f2]
#pragma unroll
    for (int a = 0; a < 4; ++a)
#pragma unroll
        for (int c = 0; c < 2; ++c) acc[a][c] = f32x4{0.f, 0.f, 0.f, 0.f};

    {   // prime chunk 0
        float4 a0 = *(const float4*)xsrc;
        float4 a1 = *(const float4*)(xsrc + 4);
        bf16x8 v;
        v[0]=f2bf(a0.x); v[1]=f2bf(a0.y); v[2]=f2bf(a0.z); v[3]=f2bf(a0.w);
        v[4]=f2bf(a1.x); v[5]=f2bf(a1.y); v[6]=f2bf(a1.z); v[7]=f2bf(a1.w);
        *(bf16x8*)&sm.A[0][srow][sseg * 8] = v;
    }
    __syncthreads();

    for (int kc = 0; kc < 16; ++kc) {
        const int cur = kc & 1;
        float4 a0, a1;
        if (kc < 15) {                 // next chunk's HBM loads fly first
            const float* nx = xsrc + (kc + 1) * 64;
            a0 = *(const float4*)nx;
            a1 = *(const float4*)(nx + 4);
        }
        // B frags straight from global W-image (each = contiguous 1KB/wave)
        const short* wc = wsrc + (size_t)kc * 8192;
        bf16x8 bfr[2][2];
#pragma unroll
        for (int kk = 0; kk < 2; ++kk)
#pragma unroll
            for (int f2 = 0; f2 < 2; ++f2)
                bfr[kk][f2] = *(const bf16x8*)&wc[(((kk * 8 + fb + f2) * 16 + l16) * 4 + quad) * 8];

#pragma unroll
        for (int kk = 0; kk < 2; ++kk)
#pragma unroll
            for (int mf = 0; mf < 4; ++mf) {
                bf16x8 af = *(const bf16x8*)&sm.A[cur][mf * 16 + l16][kk * 32 + quad * 8];
#pragma unroll
                for (int f2 = 0; f2 < 2; ++f2)
                    acc[mf][f2] = __builtin_amdgcn_mfma_f32_16x16x32_bf16(af, bfr[kk][f2], acc[mf][f2], 0, 0, 0);
            }

        if (kc < 15) {                 // stage next chunk
            bf16x8 v;
            v[0]=f2bf(a0.x); v[1]=f2bf(a0.y); v[2]=f2bf(a0.z); v[3]=f2bf(a0.w);
            v[4]=f2bf(a1.x); v[5]=f2bf(a1.y); v[6]=f2bf(a1.z); v[7]=f2bf(a1.w);
            *(bf16x8*)&sm.A[cur ^ 1][srow][sseg * 8] = v;
        }
        __syncthreads();
    }

    // ---- epilogue: scatter C into both output fragment images in LDS ----
#pragma unroll
    for (int mf = 0; mf < 4; ++mf)
#pragma unroll
        for (int f2 = 0; f2 < 2; ++f2)
#pragma unroll
            for (int r = 0; r < 4; ++r) {
                const int row = mf * 16 + quad * 4 + r;          // j within tile
                const int h   = (fb + f2) * 16 + l16;            // col within half
                int idx;
                if (nh == 0)
                    idx = ((((h >> 5) * 4 + (row >> 4)) * 16 + (row & 15)) * 4 + ((h >> 3) & 3)) * 8 + (h & 7);
                else
                    idx = 8192 + ((((row >> 5) * 8 + (h >> 4)) * 16 + (h & 15)) * 4 + ((row >> 3) & 3)) * 8 + (row & 7);
                sm.ep[idx] = f2bf(acc[mf][f2][r]);
            }
    __syncthreads();

    {   // copy out 32KB, unit-interleaved
#pragma unroll
        for (int i = 0; i < 4; ++i) {
            const int g = i * 512 + tid;       // 16B unit 0..2047
            short* dst = (g < 1024) ? (Kimg + (size_t)mt * 8192 + g * 8)
                                    : (Vimg + (size_t)mt * 8192 + (g - 1024) * 8);
            *(bf16x8*)dst = *(const bf16x8*)&sm.ep[g * 8];
        }
    }
}

// ---------------------------------------------------------------------------
// attn_kernel v13 (R16): attn v8 VERBATIM + V DOUBLE-BUFFER (one change).
//
// EVIDENCE CHAIN: v9 (V->regs, ~250cy cover) = 3490 cy/iter; v8 (V->LDS,
// ~300cy cover) = 2180 cy/iter; v12 (-33% LDS reads) = no gain. The only
// uncovered latency in v8's loop is the mid-iter vmcnt(4) waiting on V[jt]
// glds issued ~300cy earlier vs ~500-900cy L2 latency under contention.
// K never stalls because it is prefetched a FULL iteration ahead.
//
// v13: V gets the same treatment as K. Prologue stages K[0]+V[0]; each iter
// prefetches V[jt+1]+K[jt+1] into the cur^1 slots right after the top
// barrier; mid-wait drops its vmcnt entirely (lgkmcnt(0) for ps only); top
// vmcnt(0) drains loads issued a full iteration ago (~2000cy cover).
// Buffer-reuse safety = same argument as the verified K dbuf (writes to
// cur^1 only after the barrier ending all reads of it). LDS 52.5->68.5 KB,
// still 2 blocks/CU. All fragment math/swizzles/merge byte-identical to v8.
// ---------------------------------------------------------------------------
#define LOG2E 1.4426950408889634f

__global__ __launch_bounds__(256, 2)
void attn_kernel(const short* __restrict__ Kimg,  // [8][32] images
                 const short* __restrict__ Vimg,  // [8][32] images
                 float* __restrict__ out)         // [B, T, H] fp32
{
    __shared__ __align__(16) short kbuf[2][8192]; // 32 KB K tile dbuf
    __shared__ __align__(16) short vbuf[2][8192]; // 32 KB V tile dbuf
    __shared__ __align__(16) short ps[2][1024];   // per-q-tile swizzled P (16x64)
    __shared__ float lsum[4][16];                 // per-wave l partials

    const int tid  = threadIdx.x;
    const int wave = tid >> 6;
    const int lane = tid & 63;
    const int quad = lane >> 4;
    const int l16  = lane & 15;

    const int b    = blockIdx.x & 7;              // XCD-affinity
    const int gg   = blockIdx.x >> 3;             // 0..63
    const int G    = (blockIdx.x < 256) ? (63 - gg) : (gg - 32); // heavy first
    const int qsel = wave >> 1;                   // which q-tile of the pair
    const int p    = wave & 1;                    // js-half (S) / h-half (PV)
    const int qt   = 2 * G + qsel;
    const int n    = (G >> 1) + 1;                // identical for both q-tiles

    const short* Kb = Kimg + (size_t)b * 32 * 8192;
    const short* Vb = Vimg + (size_t)b * 32 * 8192;

    // Q fragments from the diagonal K-image (Q = K projection)
    bf16x8 qf[4];
    {
        const short* qi = Kb + (size_t)(qt >> 2) * 8192;
        const int jsq = qt & 3;
#pragma unroll
        for (int kc = 0; kc < 4; ++kc)
            qf[kc] = *(const bf16x8*)&qi[(((kc * 4 + jsq) * 16 + l16) * 4 + quad) * 8];
    }

    f32x4 O[4];                                   // h-half: 16q x 64h
#pragma unroll
    for (int f = 0; f < 4; ++f) O[f] = f32x4{0.f, 0.f, 0.f, 0.f};
    float lp[4] = {0.f, 0.f, 0.f, 0.f};

    const float coef = LOG2E * 0.03125f;          // log2(e)/sqrt(C), sqrt(1024)=32
    short* psq = ps[qsel];

    {   // prologue: stage K[0] AND V[0] (wave w copies 4KB of each)
        const short* sk = Kb + wave * 2048 + lane * 8;
        const short* sv = Vb + wave * 2048 + lane * 8;
#pragma unroll
        for (int i = 0; i < 4; ++i)
            glds16(sk + i * 512, &kbuf[0][wave * 2048 + i * 512]);
#pragma unroll
        for (int i = 0; i < 4; ++i)
            glds16(sv + i * 512, &vbuf[0][wave * 2048 + i * 512]);
    }

    int cur = 0;
    for (int jt = 0; jt < n; ++jt) {
        // K[jt]+V[jt] glds done (issued a full iter ago); barrier => all
        // segments visible AND all waves past prev-iter kbuf/vbuf/ps reads.
        asm volatile("s_waitcnt vmcnt(0)" ::: "memory");
        __builtin_amdgcn_s_barrier();

        const bool more = (jt + 1 < n);
        if (more) {   // prefetch V[jt+1]+K[jt+1] into cur^1 (drained next top)
            const short* sv = Vb + (size_t)(jt + 1) * 8192 + wave * 2048 + lane * 8;
            const short* sk = Kb + (size_t)(jt + 1) * 8192 + wave * 2048 + lane * 8;
#pragma unroll
            for (int i = 0; i < 4; ++i)
                glds16(sv + i * 512, &vbuf[cur ^ 1][wave * 2048 + i * 512]);
#pragma unroll
            for (int i = 0; i < 4; ++i)
                glds16(sk + i * 512, &kbuf[cur ^ 1][wave * 2048 + i * 512]);
        }

        // ---- S = Q K^T for this wave's js-half (from LDS, layout == image) ----
        const short* kt = kbuf[cur];
        f32x4 S[2];
        S[0] = f32x4{0.f, 0.f, 0.f, 0.f};
        S[1] = f32x4{0.f, 0.f, 0.f, 0.f};
#pragma unroll
        for (int kc = 0; kc < 4; ++kc)
#pragma unroll
            for (int j2 = 0; j2 < 2; ++j2) {
                bf16x8 kf = *(const bf16x8*)&kt[((kc * 4 + p * 2 + j2) * 64 + l16 * 4 + quad) * 8];
                S[j2] = __builtin_amdgcn_mfma_f32_16x16x32_bf16(qf[kc], kf, S[j2], 0, 0, 0);
            }

        // ---- P = exp2(S*coef), causal mask on diag tile; swizzled ps write ----
        const bool diag = (jt == n - 1);
#pragma unroll
        for (int j2 = 0; j2 < 2; ++j2) {
            const int js = p * 2 + j2;
            const int jj = jt * 64 + js * 16 + l16;
            const int cb = js * 2 + (l16 >> 3);
            const int e  = l16 & 7;
#pragma unroll
            for (int r = 0; r < 4; ++r) {
                float vv = S[j2][r] * coef;
                if (diag && (jj > qt * 16 + quad * 4 + r)) vv = -INFINITY;
                float pe = exp2f(vv);             // exp2(-inf) = 0
                lp[r] += pe;
                const int i8 = quad * 4 + r;
                psq[(i8 * 8 + (cb ^ (i8 & 7))) * 8 + e] = f2bf(pe);
            }
        }

        // ps writes visible; V[jt] already resident (landed before top
        // barrier); K[jt+1]/V[jt+1] glds stay in flight across the barrier.
        asm volatile("s_waitcnt lgkmcnt(0)" ::: "memory");
        __builtin_amdgcn_s_barrier();

        // ---- O += P V for this wave's h-half (pa from shared ps) ----
        const short* vt = vbuf[cur];
#pragma unroll
        for (int jc = 0; jc < 2; ++jc) {
            const int pblk = l16 * 8 + ((jc * 4 + quad) ^ (l16 & 7));
            bf16x8 pa = *(const bf16x8*)&psq[pblk * 8];
#pragma unroll
            for (int fo = 0; fo < 4; ++fo) {
                bf16x8 vf = *(const bf16x8*)&vt[((jc * 8 + p * 4 + fo) * 64 + l16 * 4 + quad) * 8];
                O[fo] = __builtin_amdgcn_mfma_f32_16x16x32_bf16(pa, vf, O[fo], 0, 0, 0);
            }
        }
        cur ^= 1;
    }

    // ---- l: reduce this wave's js-half partials across the row's 16 lanes ----
#pragma unroll
    for (int r = 0; r < 4; ++r) {
        float s = lp[r];
        s += __shfl_xor(s, 1);
        s += __shfl_xor(s, 2);
        s += __shfl_xor(s, 4);
        s += __shfl_xor(s, 8);
        lp[r] = s;
    }
    if (l16 == 0) {
#pragma unroll
        for (int r = 0; r < 4; ++r) lsum[wave][quad * 4 + r] = lp[r];
    }
    __syncthreads();

    // ---- store: each wave owns a disjoint (q-tile, h-half); no O merge ----
#pragma unroll
    for (int r = 0; r < 4; ++r) {
        const int row16 = quad * 4 + r;
        const float L   = lsum[qsel * 2][row16] + lsum[qsel * 2 + 1][row16];
        const float inv = 1.f / L;
        const int row   = qt * 16 + row16;
        float* dst = out + (size_t)(b * SEQ + row) * HD + p * 64 + l16;
#pragma unroll
        for (int fo = 0; fo < 4; ++fo)
            dst[fo * 16] = O[fo][r] * inv;
    }
}

extern "C" void kernel_launch(void* const* d_in, const int* in_sizes, int n_in,
                              void* d_out, int out_size, void* d_ws, size_t ws_size,
                              hipStream_t stream) {
    const float* x  = (const float*)d_in[0];
    const float* Wk = (const float*)d_in[1];
    // d_in[2] = Wq is UNUSED: reference uses the key projection for q (source bug)
    const float* Wv = (const float*)d_in[3];
    float* out = (float*)d_out;

    short* Wimg = (short*)d_ws;                          // 512 KB
    short* Kimg = Wimg + (size_t)262144;                 // 4 MB
    short* Vimg = Kimg + (size_t)BATCH * 32 * 8192;      // 4 MB

    prep_w<<<128, 256, 0, stream>>>(Wk, Wv, Wimg);
    proj_kernel<<<256, 512, 0, stream>>>(x, Wimg, Kimg, Vimg);
    attn_kernel<<<512, 256, 0, stream>>>(Kimg, Vimg, out);
}

// Round 8
// 143.701 us; speedup vs baseline: 1.0775x; 1.0775x over previous
//
#include <hip/hip_runtime.h>
#include <hip/hip_bf16.h>

// Problem constants (B,T,C,H from reference)
#define BATCH 8
#define SEQ   2048
#define EMB   1024
#define HD    128

typedef __attribute__((ext_vector_type(8))) short bf16x8;  // MFMA A/B frag (4 VGPR)
typedef __attribute__((ext_vector_type(4))) float f32x4;   // MFMA C/D frag

__device__ __forceinline__ short f2bf(float f) {           // RNE
    union { float f; unsigned u; } v; v.f = f;
    unsigned r = v.u + 0x7fffu + ((v.u >> 16) & 1u);
    return (short)(r >> 16);
}

// async global->LDS 16B/lane copy (wave-uniform LDS base + lane*16, per-lane src)
__device__ __forceinline__ void glds16(const short* g, short* l) {
    __builtin_amdgcn_global_load_lds(
        (const __attribute__((address_space(1))) unsigned int*)g,
        (__attribute__((address_space(3))) unsigned int*)l, 16, 0, 0);
}

// ===========================================================================
// FRAGMENT-IMAGE LAYOUTS (R6-verified): every MFMA fragment = one contiguous
// 1KB region = one fully-coalesced 16B/lane load for the consuming wave.
// W image (nh 0=K,1=V; k-chunk kc): slot(kk,f,l,q) -> W[nh*128+f*16+l][kc*64+kk*32+q*8+e]
// K image (b, jt): slot(kc,js,l,q) -> K[js*16+l][kc*32+q*8+e]
// V image (b, jt): slot(jc,f,l,q)  -> V[jc*32+q*8+e][f*16+l]
// ===========================================================================

__global__ void prep_w(const float* __restrict__ Wk, const float* __restrict__ Wv,
                       short* __restrict__ Wimg) {
    int g  = blockIdx.x * 256 + threadIdx.x;   // 0..32767
    int q  = g & 3;
    int l  = (g >> 2) & 15;
    int f  = (g >> 6) & 7;
    int kk = (g >> 9) & 1;
    int kc = (g >> 10) & 15;
    int nh = (g >> 14) & 1;
    const float* src = (nh ? Wv : Wk) + (size_t)(f * 16 + l) * EMB + kc * 64 + kk * 32 + q * 8;
    float4 f0 = *(const float4*)src;
    float4 f1 = *(const float4*)(src + 4);
    bf16x8 v;
    v[0]=f2bf(f0.x); v[1]=f2bf(f0.y); v[2]=f2bf(f0.z); v[3]=f2bf(f0.w);
    v[4]=f2bf(f1.x); v[5]=f2bf(f1.y); v[6]=f2bf(f1.z); v[7]=f2bf(f1.w);
    *(bf16x8*)&Wimg[(size_t)g * 8] = v;
}

// ---------------------------------------------------------------------------
// proj_kernel v10 (R17): v8 structure VERBATIM + register prefetch only.
//
// THEORY: proj runs ~30us vs a 12us HBM floor with implied MfmaUtil ~4% --
// ~4500cy per kc vs <=1500cy of resource flow. The two exposed latencies on
// the per-kc critical path: (a) W-frags VMEM-loaded from L2 at kc top and
// consumed by MFMA the SAME iteration (~300-500cy L2 latency x16 kc);
// (b) x-chunk staged at iter end waits on an HBM load issued ~600cy earlier.
// R2's M=32 restructure failure bundled these fixes with 3 regressions
// (M=32, 2x W-traffic, strided epilogue); here ONLY the prefetches are
// applied to the thrice-verified v8 body: W-frags for kc+1 load into nw at
// iter top (MFMA consumes last iter's bw -- full-iter cover); x pipelined
// 2 chunks ahead (~2-iter HBM cover). Same grid/tile/LDS/epilogue/stores.
// ---------------------------------------------------------------------------
__global__ __launch_bounds__(512, 2)
void proj_kernel(const float* __restrict__ x, const short* __restrict__ Wimg,
                 short* __restrict__ Kimg,    // [8][32] 16KB images
                 short* __restrict__ Vimg)    // [8][32] 16KB images
{
    __shared__ __align__(16) union {
        short A[2][64][72];          // 18.4 KB A staging dbuf (+8 pad rows)
        short ep[16384];             // 32 KB epilogue: [K image | V image]
    } sm;

    const int tid  = threadIdx.x;
    const int wave = tid >> 6;
    const int lane = tid & 63;
    const int quad = lane >> 4;
    const int l16  = lane & 15;
    const int nh   = wave >> 2;        // 0 = K half, 1 = V half
    const int fb   = (wave & 3) * 2;   // f-pair base within the half
    const int mt   = blockIdx.x;       // 0..255 (64-row tile)
    const int row0 = mt * 64;

    const int srow = tid >> 3, sseg = tid & 7;
    const float* xsrc = x + (size_t)(row0 + srow) * EMB + sseg * 8;
    const short* wsrc = Wimg + (size_t)nh * 131072;

    f32x4 acc[4][2];                   // [mf][f2]
#pragma unroll
    for (int a = 0; a < 4; ++a)
#pragma unroll
        for (int c = 0; c < 2; ++c) acc[a][c] = f32x4{0.f, 0.f, 0.f, 0.f};

    float4 p0, p1;                     // x chunk kc+1 (staged at end of iter kc)
    bf16x8 bw[2][2];                   // W frags for current kc (prefetched)
    {   // prime: chunk0 -> LDS[0]; chunk1 -> regs; W(kc=0) -> regs
        float4 a0 = *(const float4*)xsrc;
        float4 a1 = *(const float4*)(xsrc + 4);
        bf16x8 v;
        v[0]=f2bf(a0.x); v[1]=f2bf(a0.y); v[2]=f2bf(a0.z); v[3]=f2bf(a0.w);
        v[4]=f2bf(a1.x); v[5]=f2bf(a1.y); v[6]=f2bf(a1.z); v[7]=f2bf(a1.w);
        *(bf16x8*)&sm.A[0][srow][sseg * 8] = v;
        p0 = *(const float4*)(xsrc + 64);
        p1 = *(const float4*)(xsrc + 68);
#pragma unroll
        for (int kk = 0; kk < 2; ++kk)
#pragma unroll
            for (int f2 = 0; f2 < 2; ++f2)
                bw[kk][f2] = *(const bf16x8*)&wsrc[(((kk * 8 + fb + f2) * 16 + l16) * 4 + quad) * 8];
    }
    __syncthreads();

    for (int kc = 0; kc < 16; ++kc) {
        const int cur = kc & 1;
        float4 n0, n1;
        if (kc < 14) {                 // x chunk kc+2: ~2 iters of HBM cover
            const float* nx = xsrc + (kc + 2) * 64;
            n0 = *(const float4*)nx;
            n1 = *(const float4*)(nx + 4);
        }
        bf16x8 nw[2][2];
        if (kc < 15) {                 // W frags kc+1: full iter of L2 cover
            const short* wn = wsrc + (size_t)(kc + 1) * 8192;
#pragma unroll
            for (int kk = 0; kk < 2; ++kk)
#pragma unroll
                for (int f2 = 0; f2 < 2; ++f2)
                    nw[kk][f2] = *(const bf16x8*)&wn[(((kk * 8 + fb + f2) * 16 + l16) * 4 + quad) * 8];
        }

#pragma unroll
        for (int kk = 0; kk < 2; ++kk)
#pragma unroll
            for (int mf = 0; mf < 4; ++mf) {
                bf16x8 af = *(const bf16x8*)&sm.A[cur][mf * 16 + l16][kk * 32 + quad * 8];
#pragma unroll
                for (int f2 = 0; f2 < 2; ++f2)
                    acc[mf][f2] = __builtin_amdgcn_mfma_f32_16x16x32_bf16(af, bw[kk][f2], acc[mf][f2], 0, 0, 0);
            }

        if (kc < 15) {                 // stage chunk kc+1 (loaded a full iter ago)
            bf16x8 v;
            v[0]=f2bf(p0.x); v[1]=f2bf(p0.y); v[2]=f2bf(p0.z); v[3]=f2bf(p0.w);
            v[4]=f2bf(p1.x); v[5]=f2bf(p1.y); v[6]=f2bf(p1.z); v[7]=f2bf(p1.w);
            *(bf16x8*)&sm.A[cur ^ 1][srow][sseg * 8] = v;
#pragma unroll
            for (int kk = 0; kk < 2; ++kk)
#pragma unroll
                for (int f2 = 0; f2 < 2; ++f2) bw[kk][f2] = nw[kk][f2];
        }
        if (kc < 14) { p0 = n0; p1 = n1; }
        __syncthreads();
    }

    // ---- epilogue: scatter C into both output fragment images in LDS ----
#pragma unroll
    for (int mf = 0; mf < 4; ++mf)
#pragma unroll
        for (int f2 = 0; f2 < 2; ++f2)
#pragma unroll
            for (int r = 0; r < 4; ++r) {
                const int row = mf * 16 + quad * 4 + r;          // j within tile
                const int h   = (fb + f2) * 16 + l16;            // col within half
                int idx;
                if (nh == 0)
                    idx = ((((h >> 5) * 4 + (row >> 4)) * 16 + (row & 15)) * 4 + ((h >> 3) & 3)) * 8 + (h & 7);
                else
                    idx = 8192 + ((((row >> 5) * 8 + (h >> 4)) * 16 + (h & 15)) * 4 + ((row >> 3) & 3)) * 8 + (row & 7);
                sm.ep[idx] = f2bf(acc[mf][f2][r]);
            }
    __syncthreads();

    {   // copy out 32KB, unit-interleaved
#pragma unroll
        for (int i = 0; i < 4; ++i) {
            const int g = i * 512 + tid;       // 16B unit 0..2047
            short* dst = (g < 1024) ? (Kimg + (size_t)mt * 8192 + g * 8)
                                    : (Vimg + (size_t)mt * 8192 + (g - 1024) * 8);
            *(bf16x8*)dst = *(const bf16x8*)&sm.ep[g * 8];
        }
    }
}

// ---------------------------------------------------------------------------
// attn_kernel v8 VERBATIM (R10-verified ~30us -- BEST attn measured; every
// restructure since regressed: v9 V->regs 48us, v10 1blk/CU 42us, v11
// phase-lambda 100us, v12 dedup 33us, v13 V-dbuf 44us. LDS must stay at
// 52.25KB: >=56KB variants all landed 42-48us (3rd co-resident block slot
// lost). DO NOT TOUCH.): LDS-shared K/V flash attention, q == k. Block =
// q-tile pair (2G,2G+1), identical tile count n=(G>>1)+1. K dbuf prefetched
// 1 tile ahead (glds + counted vmcnt + raw s_barrier); V staged under the
// S/softmax phase. No O merge (disjoint h halves).
// ---------------------------------------------------------------------------
#define LOG2E 1.4426950408889634f

__global__ __launch_bounds__(256, 2)
void attn_kernel(const short* __restrict__ Kimg,  // [8][32] images
                 const short* __restrict__ Vimg,  // [8][32] images
                 float* __restrict__ out)         // [B, T, H] fp32
{
    __shared__ __align__(16) short kbuf[2][8192]; // 32 KB K tile dbuf
    __shared__ __align__(16) short vbuf[8192];    // 16 KB V tile
    __shared__ __align__(16) short ps[2][1024];   // per-q-tile swizzled P (16x64)
    __shared__ float lsum[4][16];                 // per-wave l partials

    const int tid  = threadIdx.x;
    const int wave = tid >> 6;
    const int lane = tid & 63;
    const int quad = lane >> 4;
    const int l16  = lane & 15;

    const int b    = blockIdx.x & 7;              // XCD-affinity
    const int gg   = blockIdx.x >> 3;             // 0..63
    const int G    = (blockIdx.x < 256) ? (63 - gg) : (gg - 32); // heavy first
    const int qsel = wave >> 1;                   // which q-tile of the pair
    const int p    = wave & 1;                    // js-half (S) / h-half (PV)
    const int qt   = 2 * G + qsel;
    const int n    = (G >> 1) + 1;                // identical for both q-tiles

    const short* Kb = Kimg + (size_t)b * 32 * 8192;
    const short* Vb = Vimg + (size_t)b * 32 * 8192;

    // Q fragments from the diagonal K-image (Q = K projection)
    bf16x8 qf[4];
    {
        const short* qi = Kb + (size_t)(qt >> 2) * 8192;
        const int jsq = qt & 3;
#pragma unroll
        for (int kc = 0; kc < 4; ++kc)
            qf[kc] = *(const bf16x8*)&qi[(((kc * 4 + jsq) * 16 + l16) * 4 + quad) * 8];
    }

    f32x4 O[4];
#pragma unroll
    for (int f = 0; f < 4; ++f) O[f] = f32x4{0.f, 0.f, 0.f, 0.f};
    float lp[4] = {0.f, 0.f, 0.f, 0.f};

    const float coef = LOG2E * 0.03125f;   // log2(e)/sqrt(C), sqrt(1024)=32
    short* psq = ps[qsel];

    {   // prologue: stage K tile 0 (wave w copies 4KB: 4 x 1KB glds)
        const short* sk = Kb + wave * 2048 + lane * 8;
#pragma unroll
        for (int i = 0; i < 4; ++i)
            glds16(sk + i * 512, &kbuf[0][wave * 2048 + i * 512]);
    }

    int cur = 0;
    for (int jt = 0; jt < n; ++jt) {
        // K[jt] (my 4 glds) done; barrier => all segments visible AND all
        // waves finished reading vbuf/ps/kbuf[cur^1] from the previous step.
        asm volatile("s_waitcnt vmcnt(0)" ::: "memory");
        __builtin_amdgcn_s_barrier();

        {   // stage V[jt] (needed at PV this step -- oldest in flight)
            const short* sv = Vb + (size_t)jt * 8192 + wave * 2048 + lane * 8;
#pragma unroll
            for (int i = 0; i < 4; ++i)
                glds16(sv + i * 512, &vbuf[wave * 2048 + i * 512]);
        }
        const bool more = (jt + 1 < n);
        if (more) {   // prefetch K[jt+1] (drained at next step's loop top)
            const short* sk = Kb + (size_t)(jt + 1) * 8192 + wave * 2048 + lane * 8;
#pragma unroll
            for (int i = 0; i < 4; ++i)
                glds16(sk + i * 512, &kbuf[cur ^ 1][wave * 2048 + i * 512]);
        }

        // ---- S = Q K^T for this wave's js-half (from LDS, layout == image) ----
        const short* kt = kbuf[cur];
        f32x4 S[2];
        S[0] = f32x4{0.f, 0.f, 0.f, 0.f};
        S[1] = f32x4{0.f, 0.f, 0.f, 0.f};
#pragma unroll
        for (int kc = 0; kc < 4; ++kc)
#pragma unroll
            for (int j2 = 0; j2 < 2; ++j2) {
                bf16x8 kf = *(const bf16x8*)&kt[((kc * 4 + p * 2 + j2) * 64 + l16 * 4 + quad) * 8];
                S[j2] = __builtin_amdgcn_mfma_f32_16x16x32_bf16(qf[kc], kf, S[j2], 0, 0, 0);
            }

        // ---- P = exp2(S*coef), causal mask on diag tile; swizzled ps write ----
        const bool diag = (jt == n - 1);
#pragma unroll
        for (int j2 = 0; j2 < 2; ++j2) {
            const int js = p * 2 + j2;
            const int jj = jt * 64 + js * 16 + l16;
            const int cb = js * 2 + (l16 >> 3);
            const int e  = l16 & 7;
#pragma unroll
            for (int r = 0; r < 4; ++r) {
                float vv = S[j2][r] * coef;
                if (diag && (jj > qt * 16 + quad * 4 + r)) vv = -INFINITY;
                float pe = exp2f(vv);            // exp2(-inf) = 0
                lp[r] += pe;
                const int i8 = quad * 4 + r;
                psq[(i8 * 8 + (cb ^ (i8 & 7))) * 8 + e] = f2bf(pe);
            }
        }

        // V[jt] landed (oldest 4), K[jt+1] stays in flight; ps writes visible.
        if (more) asm volatile("s_waitcnt vmcnt(4) lgkmcnt(0)" ::: "memory");
        else      asm volatile("s_waitcnt vmcnt(0) lgkmcnt(0)" ::: "memory");
        __builtin_amdgcn_s_barrier();

        // ---- O += P V for this wave's h-half (full P from shared ps) ----
#pragma unroll
        for (int jc = 0; jc < 2; ++jc) {
            const int pblk = l16 * 8 + ((jc * 4 + quad) ^ (l16 & 7));
            bf16x8 pa = *(const bf16x8*)&psq[pblk * 8];
#pragma unroll
            for (int fo = 0; fo < 4; ++fo) {
                bf16x8 vf = *(const bf16x8*)&vbuf[((jc * 8 + p * 4 + fo) * 64 + l16 * 4 + quad) * 8];
                O[fo] = __builtin_amdgcn_mfma_f32_16x16x32_bf16(pa, vf, O[fo], 0, 0, 0);
            }
        }
        cur ^= 1;
    }

    // ---- l: reduce across the row's 16 lanes ----
#pragma unroll
    for (int r = 0; r < 4; ++r) {
        float s = lp[r];
        s += __shfl_xor(s, 1);
        s += __shfl_xor(s, 2);
        s += __shfl_xor(s, 4);
        s += __shfl_xor(s, 8);
        lp[r] = s;
    }
    if (l16 == 0) {
#pragma unroll
        for (int r = 0; r < 4; ++r) lsum[wave][quad * 4 + r] = lp[r];
    }
    __syncthreads();

    // ---- store: each wave owns a disjoint (q-tile, h-half); no O merge ----
#pragma unroll
    for (int r = 0; r < 4; ++r) {
        const int row16 = quad * 4 + r;
        const float L   = lsum[qsel * 2][row16] + lsum[qsel * 2 + 1][row16];
        const float inv = 1.f / L;
        const int row   = qt * 16 + row16;
        float* dst = out + (size_t)(b * SEQ + row) * HD + p * 64 + l16;
#pragma unroll
        for (int fo = 0; fo < 4; ++fo)
            dst[fo * 16] = O[fo][r] * inv;
    }
}

extern "C" void kernel_launch(void* const* d_in, const int* in_sizes, int n_in,
                              void* d_out, int out_size, void* d_ws, size_t ws_size,
                              hipStream_t stream) {
    const float* x  = (const float*)d_in[0];
    const float* Wk = (const float*)d_in[1];
    // d_in[2] = Wq is UNUSED: reference uses the key projection for q (source bug)
    const float* Wv = (const float*)d_in[3];
    float* out = (float*)d_out;

    short* Wimg = (short*)d_ws;                          // 512 KB
    short* Kimg = Wimg + (size_t)262144;                 // 4 MB
    short* Vimg = Kimg + (size_t)BATCH * 32 * 8192;      // 4 MB

    prep_w<<<128, 256, 0, stream>>>(Wk, Wv, Wimg);
    proj_kernel<<<256, 512, 0, stream>>>(x, Wimg, Kimg, Vimg);
    attn_kernel<<<512, 256, 0, stream>>>(Kimg, Vimg, out);
}

// Round 9
// 142.581 us; speedup vs baseline: 1.0859x; 1.0079x over previous
//
#include <hip/hip_runtime.h>
#include <hip/hip_bf16.h>

// Problem constants (B,T,C,H from reference)
#define BATCH 8
#define SEQ   2048
#define EMB   1024
#define HD    128

typedef __attribute__((ext_vector_type(8))) short bf16x8;  // MFMA A/B frag (4 VGPR)
typedef __attribute__((ext_vector_type(4))) float f32x4;   // MFMA C/D frag

__device__ __forceinline__ short f2bf(float f) {           // RNE
    union { float f; unsigned u; } v; v.f = f;
    unsigned r = v.u + 0x7fffu + ((v.u >> 16) & 1u);
    return (short)(r >> 16);
}

// async global->LDS 16B/lane copy (wave-uniform LDS base + lane*16, per-lane src)
__device__ __forceinline__ void glds16(const short* g, short* l) {
    __builtin_amdgcn_global_load_lds(
        (const __attribute__((address_space(1))) unsigned int*)g,
        (__attribute__((address_space(3))) unsigned int*)l, 16, 0, 0);
}

// ===========================================================================
// FRAGMENT-IMAGE LAYOUTS (R6-verified): every MFMA fragment = one contiguous
// 1KB region = one fully-coalesced 16B/lane load for the consuming wave.
// W image (nh 0=K,1=V; k-chunk kc): slot(kk,f,l,q) -> W[nh*128+f*16+l][kc*64+kk*32+q*8+e]
// K image (b, jt): slot(kc,js,l,q) -> K[js*16+l][kc*32+q*8+e]
// V image (b, jt): slot(jc,f,l,q)  -> V[jc*32+q*8+e][f*16+l]
// ===========================================================================

__global__ void prep_w(const float* __restrict__ Wk, const float* __restrict__ Wv,
                       short* __restrict__ Wimg) {
    int g  = blockIdx.x * 256 + threadIdx.x;   // 0..32767
    int q  = g & 3;
    int l  = (g >> 2) & 15;
    int f  = (g >> 6) & 7;
    int kk = (g >> 9) & 1;
    int kc = (g >> 10) & 15;
    int nh = (g >> 14) & 1;
    const float* src = (nh ? Wv : Wk) + (size_t)(f * 16 + l) * EMB + kc * 64 + kk * 32 + q * 8;
    float4 f0 = *(const float4*)src;
    float4 f1 = *(const float4*)(src + 4);
    bf16x8 v;
    v[0]=f2bf(f0.x); v[1]=f2bf(f0.y); v[2]=f2bf(f0.z); v[3]=f2bf(f0.w);
    v[4]=f2bf(f1.x); v[5]=f2bf(f1.y); v[6]=f2bf(f1.z); v[7]=f2bf(f1.w);
    *(bf16x8*)&Wimg[(size_t)g * 8] = v;
}

// ---------------------------------------------------------------------------
// proj_kernel v11 (R18): v10 dataflow + RAW BARRIERS (counted waits).
//
// ROOT CAUSE (explains v10's neutrality AND v8's ~30us): __syncthreads()
// lowers to "s_waitcnt vmcnt(0) lgkmcnt(0); s_barrier" -- every per-kc
// barrier DRAINED all in-flight x/W register prefetches, so each kc paid
// full HBM latency + BW-pipeline restart (~4500cy/kc measured vs ~1560cy
// flow floor). attn v8 (raw s_barrier + counted vmcnt) never had this.
//
// v11: in-loop barriers become "s_waitcnt lgkmcnt(0); s_barrier" (the attn-
// v8-verified idiom). LDS producer/consumer ordering is fully provided by
// lgkmcnt(0)+barrier; x/W loads target PRIVATE REGISTERS and legally stay
// in flight across barriers -- the compiler inserts counted vmcnt at their
// use points (ds_write of staged chunk / MFMA of bw), each ~1.5-2 iters
// after issue. All pipeline buffers are NAMED registers (pxA/pxB, bwA/bwB)
// rotated by a 2-step macro -- no runtime-indexed register arrays (scratch
// hazard). Chunk c lives in slot c&1; W(kc) in slot kc&1. Grid/tile/LDS/
// epilogue/stores byte-identical to v8/v10.
// ---------------------------------------------------------------------------
__global__ __launch_bounds__(512, 2)
void proj_kernel(const float* __restrict__ x, const short* __restrict__ Wimg,
                 short* __restrict__ Kimg,    // [8][32] 16KB images
                 short* __restrict__ Vimg)    // [8][32] 16KB images
{
    __shared__ __align__(16) union {
        short A[2][64][72];          // 18.4 KB A staging dbuf (+8 pad rows)
        short ep[16384];             // 32 KB epilogue: [K image | V image]
    } sm;

    const int tid  = threadIdx.x;
    const int wave = tid >> 6;
    const int lane = tid & 63;
    const int quad = lane >> 4;
    const int l16  = lane & 15;
    const int nh   = wave >> 2;        // 0 = K half, 1 = V half
    const int fb   = (wave & 3) * 2;   // f-pair base within the half
    const int mt   = blockIdx.x;       // 0..255 (64-row tile)
    const int row0 = mt * 64;

    const int srow = tid >> 3, sseg = tid & 7;
    const float* xsrc = x + (size_t)(row0 + srow) * EMB + sseg * 8;
    const short* wsrc = Wimg + (size_t)nh * 131072;

    f32x4 acc[4][2];                   // [mf][f2]
#pragma unroll
    for (int a = 0; a < 4; ++a)
#pragma unroll
        for (int c = 0; c < 2; ++c) acc[a][c] = f32x4{0.f, 0.f, 0.f, 0.f};

    float4 pxA0, pxA1, pxB0, pxB1;     // x chunks: A = even chunks, B = odd
    bf16x8 bwA[2][2], bwB[2][2];       // W frags:  A = even kc,     B = odd

    {   // prime: chunk0 -> LDS[0]; chunk1 -> pxB; W(0) -> bwA
        float4 a0 = *(const float4*)xsrc;
        float4 a1 = *(const float4*)(xsrc + 4);
        bf16x8 v;
        v[0]=f2bf(a0.x); v[1]=f2bf(a0.y); v[2]=f2bf(a0.z); v[3]=f2bf(a0.w);
        v[4]=f2bf(a1.x); v[5]=f2bf(a1.y); v[6]=f2bf(a1.z); v[7]=f2bf(a1.w);
        *(bf16x8*)&sm.A[0][srow][sseg * 8] = v;
        pxB0 = *(const float4*)(xsrc + 64);
        pxB1 = *(const float4*)(xsrc + 68);
#pragma unroll
        for (int kk = 0; kk < 2; ++kk)
#pragma unroll
            for (int f2 = 0; f2 < 2; ++f2)
                bwA[kk][f2] = *(const bf16x8*)&wsrc[(((kk * 8 + fb + f2) * 16 + l16) * 4 + quad) * 8];
    }
    asm volatile("s_waitcnt lgkmcnt(0)" ::: "memory");
    __builtin_amdgcn_s_barrier();

// One kc step. BWC: W frags consumed this step; BWN: slot receiving W(KC+1).
// PXN0/1: regs receiving x chunk KC+2. PXS0/1: regs staged to LDS (chunk KC+1).
// CL/NL: LDS buffer read/written. DOX/DOW/DOST: literal 0/1 guards.
// Ends with lgkmcnt(0)+raw barrier: LDS ordering only; VMEM stays in flight.
#define PROJ_STEP(KC, BWC, BWN, PXN0, PXN1, PXS0, PXS1, CL, NL, DOX, DOW, DOST) \
    {                                                                           \
        if (DOX) {                                                              \
            const float* nx_ = xsrc + ((KC) + 2) * 64;                          \
            PXN0 = *(const float4*)nx_;                                         \
            PXN1 = *(const float4*)(nx_ + 4);                                   \
        }                                                                       \
        if (DOW) {                                                              \
            const short* wn_ = wsrc + (size_t)((KC) + 1) * 8192;                \
            _Pragma("unroll")                                                   \
            for (int kk = 0; kk < 2; ++kk)                                      \
                _Pragma("unroll")                                               \
                for (int f2 = 0; f2 < 2; ++f2)                                  \
                    BWN[kk][f2] = *(const bf16x8*)&wn_[(((kk * 8 + fb + f2) * 16 + l16) * 4 + quad) * 8]; \
        }                                                                       \
        _Pragma("unroll")                                                       \
        for (int kk = 0; kk < 2; ++kk)                                          \
            _Pragma("unroll")                                                   \
            for (int mf = 0; mf < 4; ++mf) {                                    \
                bf16x8 af_ = *(const bf16x8*)&sm.A[CL][mf * 16 + l16][kk * 32 + quad * 8]; \
                _Pragma("unroll")                                               \
                for (int f2 = 0; f2 < 2; ++f2)                                  \
                    acc[mf][f2] = __builtin_amdgcn_mfma_f32_16x16x32_bf16(af_, BWC[kk][f2], acc[mf][f2], 0, 0, 0); \
            }                                                                   \
        if (DOST) {                                                             \
            bf16x8 v_;                                                          \
            v_[0]=f2bf(PXS0.x); v_[1]=f2bf(PXS0.y); v_[2]=f2bf(PXS0.z); v_[3]=f2bf(PXS0.w); \
            v_[4]=f2bf(PXS1.x); v_[5]=f2bf(PXS1.y); v_[6]=f2bf(PXS1.z); v_[7]=f2bf(PXS1.w); \
            *(bf16x8*)&sm.A[NL][srow][sseg * 8] = v_;                           \
        }                                                                       \
        asm volatile("s_waitcnt lgkmcnt(0)" ::: "memory");                      \
        __builtin_amdgcn_s_barrier();                                           \
    }

    for (int kp = 0; kp < 7; ++kp) {   // kc = 0..13 (all guards on)
        const int kc = kp * 2;
        PROJ_STEP(kc,     bwA, bwB, pxA0, pxA1, pxB0, pxB1, 0, 1, 1, 1, 1)
        PROJ_STEP(kc + 1, bwB, bwA, pxB0, pxB1, pxA0, pxA1, 1, 0, 1, 1, 1)
    }
    PROJ_STEP(14, bwA, bwB, pxA0, pxA1, pxB0, pxB1, 0, 1, 0, 1, 1)  // W15 only
    PROJ_STEP(15, bwB, bwA, pxB0, pxB1, pxA0, pxA1, 1, 0, 0, 0, 0)  // MFMA only
#undef PROJ_STEP

    // ---- epilogue: scatter C into both output fragment images in LDS ----
#pragma unroll
    for (int mf = 0; mf < 4; ++mf)
#pragma unroll
        for (int f2 = 0; f2 < 2; ++f2)
#pragma unroll
            for (int r = 0; r < 4; ++r) {
                const int row = mf * 16 + quad * 4 + r;          // j within tile
                const int h   = (fb + f2) * 16 + l16;            // col within half
                int idx;
                if (nh == 0)
                    idx = ((((h >> 5) * 4 + (row >> 4)) * 16 + (row & 15)) * 4 + ((h >> 3) & 3)) * 8 + (h & 7);
                else
                    idx = 8192 + ((((row >> 5) * 8 + (h >> 4)) * 16 + (h & 15)) * 4 + ((row >> 3) & 3)) * 8 + (row & 7);
                sm.ep[idx] = f2bf(acc[mf][f2][r]);
            }
    __syncthreads();

    {   // copy out 32KB, unit-interleaved
#pragma unroll
        for (int i = 0; i < 4; ++i) {
            const int g = i * 512 + tid;       // 16B unit 0..2047
            short* dst = (g < 1024) ? (Kimg + (size_t)mt * 8192 + g * 8)
                                    : (Vimg + (size_t)mt * 8192 + (g - 1024) * 8);
            *(bf16x8*)dst = *(const bf16x8*)&sm.ep[g * 8];
        }
    }
}

// ---------------------------------------------------------------------------
// attn_kernel v8 VERBATIM (R10-verified ~30us -- BEST attn measured; every
// restructure since regressed: v9 V->regs 48us, v10 1blk/CU 42us, v11
// phase-lambda 100us, v12 dedup 33us, v13 V-dbuf 44us. LDS must stay at
// 52.25KB: >=56KB variants all landed 42-48us (3rd co-resident block slot
// lost). DO NOT TOUCH.): LDS-shared K/V flash attention, q == k. Block =
// q-tile pair (2G,2G+1), identical tile count n=(G>>1)+1. K dbuf prefetched
// 1 tile ahead (glds + counted vmcnt + raw s_barrier); V staged under the
// S/softmax phase. No O merge (disjoint h halves).
// ---------------------------------------------------------------------------
#define LOG2E 1.4426950408889634f

__global__ __launch_bounds__(256, 2)
void attn_kernel(const short* __restrict__ Kimg,  // [8][32] images
                 const short* __restrict__ Vimg,  // [8][32] images
                 float* __restrict__ out)         // [B, T, H] fp32
{
    __shared__ __align__(16) short kbuf[2][8192]; // 32 KB K tile dbuf
    __shared__ __align__(16) short vbuf[8192];    // 16 KB V tile
    __shared__ __align__(16) short ps[2][1024];   // per-q-tile swizzled P (16x64)
    __shared__ float lsum[4][16];                 // per-wave l partials

    const int tid  = threadIdx.x;
    const int wave = tid >> 6;
    const int lane = tid & 63;
    const int quad = lane >> 4;
    const int l16  = lane & 15;

    const int b    = blockIdx.x & 7;              // XCD-affinity
    const int gg   = blockIdx.x >> 3;             // 0..63
    const int G    = (blockIdx.x < 256) ? (63 - gg) : (gg - 32); // heavy first
    const int qsel = wave >> 1;                   // which q-tile of the pair
    const int p    = wave & 1;                    // js-half (S) / h-half (PV)
    const int qt   = 2 * G + qsel;
    const int n    = (G >> 1) + 1;                // identical for both q-tiles

    const short* Kb = Kimg + (size_t)b * 32 * 8192;
    const short* Vb = Vimg + (size_t)b * 32 * 8192;

    // Q fragments from the diagonal K-image (Q = K projection)
    bf16x8 qf[4];
    {
        const short* qi = Kb + (size_t)(qt >> 2) * 8192;
        const int jsq = qt & 3;
#pragma unroll
        for (int kc = 0; kc < 4; ++kc)
            qf[kc] = *(const bf16x8*)&qi[(((kc * 4 + jsq) * 16 + l16) * 4 + quad) * 8];
    }

    f32x4 O[4];
#pragma unroll
    for (int f = 0; f < 4; ++f) O[f] = f32x4{0.f, 0.f, 0.f, 0.f};
    float lp[4] = {0.f, 0.f, 0.f, 0.f};

    const float coef = LOG2E * 0.03125f;   // log2(e)/sqrt(C), sqrt(1024)=32
    short* psq = ps[qsel];

    {   // prologue: stage K tile 0 (wave w copies 4KB: 4 x 1KB glds)
        const short* sk = Kb + wave * 2048 + lane * 8;
#pragma unroll
        for (int i = 0; i < 4; ++i)
            glds16(sk + i * 512, &kbuf[0][wave * 2048 + i * 512]);
    }

    int cur = 0;
    for (int jt = 0; jt < n; ++jt) {
        // K[jt] (my 4 glds) done; barrier => all segments visible AND all
        // waves finished reading vbuf/ps/kbuf[cur^1] from the previous step.
        asm volatile("s_waitcnt vmcnt(0)" ::: "memory");
        __builtin_amdgcn_s_barrier();

        {   // stage V[jt] (needed at PV this step -- oldest in flight)
            const short* sv = Vb + (size_t)jt * 8192 + wave * 2048 + lane * 8;
#pragma unroll
            for (int i = 0; i < 4; ++i)
                glds16(sv + i * 512, &vbuf[wave * 2048 + i * 512]);
        }
        const bool more = (jt + 1 < n);
        if (more) {   // prefetch K[jt+1] (drained at next step's loop top)
            const short* sk = Kb + (size_t)(jt + 1) * 8192 + wave * 2048 + lane * 8;
#pragma unroll
            for (int i = 0; i < 4; ++i)
                glds16(sk + i * 512, &kbuf[cur ^ 1][wave * 2048 + i * 512]);
        }

        // ---- S = Q K^T for this wave's js-half (from LDS, layout == image) ----
        const short* kt = kbuf[cur];
        f32x4 S[2];
        S[0] = f32x4{0.f, 0.f, 0.f, 0.f};
        S[1] = f32x4{0.f, 0.f, 0.f, 0.f};
#pragma unroll
        for (int kc = 0; kc < 4; ++kc)
#pragma unroll
            for (int j2 = 0; j2 < 2; ++j2) {
                bf16x8 kf = *(const bf16x8*)&kt[((kc * 4 + p * 2 + j2) * 64 + l16 * 4 + quad) * 8];
                S[j2] = __builtin_amdgcn_mfma_f32_16x16x32_bf16(qf[kc], kf, S[j2], 0, 0, 0);
            }

        // ---- P = exp2(S*coef), causal mask on diag tile; swizzled ps write ----
        const bool diag = (jt == n - 1);
#pragma unroll
        for (int j2 = 0; j2 < 2; ++j2) {
            const int js = p * 2 + j2;
            const int jj = jt * 64 + js * 16 + l16;
            const int cb = js * 2 + (l16 >> 3);
            const int e  = l16 & 7;
#pragma unroll
            for (int r = 0; r < 4; ++r) {
                float vv = S[j2][r] * coef;
                if (diag && (jj > qt * 16 + quad * 4 + r)) vv = -INFINITY;
                float pe = exp2f(vv);            // exp2(-inf) = 0
                lp[r] += pe;
                const int i8 = quad * 4 + r;
                psq[(i8 * 8 + (cb ^ (i8 & 7))) * 8 + e] = f2bf(pe);
            }
        }

        // V[jt] landed (oldest 4), K[jt+1] stays in flight; ps writes visible.
        if (more) asm volatile("s_waitcnt vmcnt(4) lgkmcnt(0)" ::: "memory");
        else      asm volatile("s_waitcnt vmcnt(0) lgkmcnt(0)" ::: "memory");
        __builtin_amdgcn_s_barrier();

        // ---- O += P V for this wave's h-half (full P from shared ps) ----
#pragma unroll
        for (int jc = 0; jc < 2; ++jc) {
            const int pblk = l16 * 8 + ((jc * 4 + quad) ^ (l16 & 7));
            bf16x8 pa = *(const bf16x8*)&psq[pblk * 8];
#pragma unroll
            for (int fo = 0; fo < 4; ++fo) {
                bf16x8 vf = *(const bf16x8*)&vbuf[((jc * 8 + p * 4 + fo) * 64 + l16 * 4 + quad) * 8];
                O[fo] = __builtin_amdgcn_mfma_f32_16x16x32_bf16(pa, vf, O[fo], 0, 0, 0);
            }
        }
        cur ^= 1;
    }

    // ---- l: reduce across the row's 16 lanes ----
#pragma unroll
    for (int r = 0; r < 4; ++r) {
        float s = lp[r];
        s += __shfl_xor(s, 1);
        s += __shfl_xor(s, 2);
        s += __shfl_xor(s, 4);
        s += __shfl_xor(s, 8);
        lp[r] = s;
    }
    if (l16 == 0) {
#pragma unroll
        for (int r = 0; r < 4; ++r) lsum[wave][quad * 4 + r] = lp[r];
    }
    __syncthreads();

    // ---- store: each wave owns a disjoint (q-tile, h-half); no O merge ----
#pragma unroll
    for (int r = 0; r < 4; ++r) {
        const int row16 = quad * 4 + r;
        const float L   = lsum[qsel * 2][row16] + lsum[qsel * 2 + 1][row16];
        const float inv = 1.f / L;
        const int row   = qt * 16 + row16;
        float* dst = out + (size_t)(b * SEQ + row) * HD + p * 64 + l16;
#pragma unroll
        for (int fo = 0; fo < 4; ++fo)
            dst[fo * 16] = O[fo][r] * inv;
    }
}

extern "C" void kernel_launch(void* const* d_in, const int* in_sizes, int n_in,
                              void* d_out, int out_size, void* d_ws, size_t ws_size,
                              hipStream_t stream) {
    const float* x  = (const float*)d_in[0];
    const float* Wk = (const float*)d_in[1];
    // d_in[2] = Wq is UNUSED: reference uses the key projection for q (source bug)
    const float* Wv = (const float*)d_in[3];
    float* out = (float*)d_out;

    short* Wimg = (short*)d_ws;                          // 512 KB
    short* Kimg = Wimg + (size_t)262144;                 // 4 MB
    short* Vimg = Kimg + (size_t)BATCH * 32 * 8192;      // 4 MB

    prep_w<<<128, 256, 0, stream>>>(Wk, Wv, Wimg);
    proj_kernel<<<256, 512, 0, stream>>>(x, Wimg, Kimg, Vimg);
    attn_kernel<<<512, 256, 0, stream>>>(Kimg, Vimg, out);
}